// Round 5
// baseline (160.500 us; speedup 1.0000x reference)
//
#include <hip/hip_runtime.h>

// ---------- types ----------
typedef __attribute__((ext_vector_type(8))) short bf16x8;   // 8 bf16 = 4 VGPR
typedef __attribute__((ext_vector_type(4))) float f32x4;
typedef __attribute__((ext_vector_type(16))) float f32x16;

#define MFMA16(A, B, C) __builtin_amdgcn_mfma_f32_16x16x32_bf16((A), (B), (C), 0, 0, 0)
#define MFMA32(A, B, C) __builtin_amdgcn_mfma_f32_32x32x16_bf16((A), (B), (C), 0, 0, 0)

union U8 { unsigned u[4]; bf16x8 v; };

// fp32 -> bf16 (round-to-nearest-even), header-independent
__device__ __forceinline__ unsigned short f2b(float f) {
  unsigned u = __builtin_bit_cast(unsigned, f);
  unsigned r = (u + 0x7fffu + ((u >> 16) & 1u)) >> 16;
  return (unsigned short)r;
}

// packed f32x2 -> bf16x2
__device__ __forceinline__ unsigned cvtpk(float lo, float hi) {
  unsigned r;
  asm("v_cvt_pk_bf16_f32 %0, %1, %2" : "=v"(r) : "v"(lo), "v"(hi));
  return r;
}
// exchange a.hi-half <-> b.lo-half across lane32 boundary
__device__ __forceinline__ void swap32(unsigned& a, unsigned& b) {
  asm("v_permlane32_swap_b32 %0, %1" : "+v"(a), "+v"(b));
}

// async global->LDS, 16B per lane. dest = wave-uniform base + lane*16
__device__ __forceinline__ void gload16(const void* g, void* l) {
  __builtin_amdgcn_global_load_lds(
      (const __attribute__((address_space(1))) void*)g,
      (__attribute__((address_space(3))) void*)l, 16, 0, 0);
}

// ---------- pre-pass: fp32 -> bf16 (vectorized) ----------
__global__ void conv_bf16_kernel(const float* __restrict__ src,
                                 unsigned short* __restrict__ dst, int n) {
  int i = (blockIdx.x * blockDim.x + threadIdx.x) * 4;
  if (i < n) {
    float4 v = *(const float4*)(src + i);
    ushort4 o;
    o.x = f2b(v.x); o.y = f2b(v.y); o.z = f2b(v.z); o.w = f2b(v.w);
    *(ushort4*)(dst + i) = o;
  }
}

// ---------- pre-pass: transpose fp32 [R][C] -> bf16 [C][R] ----------
__global__ __launch_bounds__(1024) void transpose_bf16_kernel(
    const float* __restrict__ src, unsigned short* __restrict__ dst, int R, int C) {
  __shared__ unsigned short t[32][33];
  int x = threadIdx.x, y = threadIdx.y;
  int c0 = blockIdx.x * 32, r0 = blockIdx.y * 32;
  t[y][x] = f2b(src[(size_t)(r0 + y) * C + c0 + x]);
  __syncthreads();
  dst[(size_t)(c0 + y) * R + r0 + x] = t[x][y];
}

// ---------- GEMM: C[M,N] = A[M,K] * Bt[N,K]^T (+bias), bf16 MFMA ----------
template <int MODE>
__global__ __launch_bounds__(256, 2) void gemm_bf16_kernel(
    const unsigned short* __restrict__ A, const unsigned short* __restrict__ Bt,
    const float* __restrict__ bias, int M, int N, int K,
    unsigned short* __restrict__ q_bf, unsigned short* __restrict__ k_bf,
    unsigned short* __restrict__ vt_bf, float* __restrict__ k_out,
    float* __restrict__ v_out, float* __restrict__ y_out) {
  __shared__ __align__(16) unsigned short As[128 * 64];
  __shared__ __align__(16) unsigned short Bs[128 * 64];
  const int tid = threadIdx.x;
  const int lane = tid & 63, wid = tid >> 6;
  const int wr = wid >> 1, wc = wid & 1;
  const int l15 = lane & 15, lg = lane >> 4;
  const int m0 = blockIdx.y * 128, n0 = blockIdx.x * 128;

  f32x4 acc[4][4] = {};

  int rowS[4], colS[4];
#pragma unroll
  for (int j = 0; j < 4; ++j) {
    int L = j * 4096 + wid * 1024 + lane * 16;  // linear LDS byte
    int row = L >> 7;
    int c = (L & 127) ^ ((row & 7) << 4);
    rowS[j] = row;
    colS[j] = c >> 1;  // bf16 elements
  }

  for (int kt = 0; kt < K; kt += 64) {
    __syncthreads();
#pragma unroll
    for (int j = 0; j < 4; ++j) {
      gload16(A + (size_t)(m0 + rowS[j]) * K + kt + colS[j],
              (char*)As + j * 4096 + wid * 1024);
      gload16(Bt + (size_t)(n0 + rowS[j]) * K + kt + colS[j],
              (char*)Bs + j * 4096 + wid * 1024);
    }
    __syncthreads();

    bf16x8 af[4][2], bfr[4][2];
#pragma unroll
    for (int i = 0; i < 4; ++i)
#pragma unroll
      for (int kk = 0; kk < 2; ++kk) {
        int ra = wr * 64 + i * 16 + l15;
        int cb = kk * 64 + lg * 16;
        af[i][kk] = *(const bf16x8*)((const char*)As + ra * 128 + (cb ^ ((ra & 7) << 4)));
        int rb = wc * 64 + i * 16 + l15;
        bfr[i][kk] = *(const bf16x8*)((const char*)Bs + rb * 128 + (cb ^ ((rb & 7) << 4)));
      }
#pragma unroll
    for (int mi = 0; mi < 4; ++mi)
#pragma unroll
      for (int ni = 0; ni < 4; ++ni)
#pragma unroll
        for (int kk = 0; kk < 2; ++kk)
          acc[mi][ni] = MFMA16(af[mi][kk], bfr[ni][kk], acc[mi][ni]);
  }

#pragma unroll
  for (int ni = 0; ni < 4; ++ni) {
    int gn = n0 + wc * 64 + ni * 16 + l15;
    float bv = bias[gn];
    if (MODE == 0) {
      int which = gn >> 10, rem = gn & 1023;
      int h = rem >> 6, dh = rem & 63;
#pragma unroll
      for (int mi = 0; mi < 4; ++mi) {
        int gmb = m0 + wr * 64 + mi * 16 + lg * 4;
#pragma unroll
        for (int r = 0; r < 4; ++r) {
          int gm = gmb + r;
          int b = gm >> 11, t = gm & 2047;
          float val = acc[mi][ni][r] + bv;
          size_t idx = ((size_t)((b * 16 + h) * 2048 + t)) * 64 + dh;
          if (which == 0) {
            q_bf[idx] = f2b(val * 0.18033688f);  // pre-scale by 1/sqrt(64)*log2(e)
          } else if (which == 1) {
            k_out[idx] = val;
            k_bf[idx] = f2b(val);
          } else {
            v_out[idx] = val;
            vt_bf[((size_t)(b * 16 + h) * 64 + dh) * 2048 + t] = f2b(val);
          }
        }
      }
    } else {
#pragma unroll
      for (int mi = 0; mi < 4; ++mi) {
        int gmb = m0 + wr * 64 + mi * 16 + lg * 4;
#pragma unroll
        for (int r = 0; r < 4; ++r)
          y_out[(size_t)(gmb + r) * N + gn] = acc[mi][ni][r] + bv;
      }
    }
  }
}

// ---------- causal flash attention: split-K across waves, pinned prefetch ----
// Block = (q-tile of 32 rows, head); wave w handles KV tiles t = w, w+4, ...
// Next tile's K/V loads are issued BEFORE current tile's compute and pinned
// with sched_barrier(0) so they stay in flight across the whole tile.
// Overrun prefetch on the last iteration reads unused (allocated) ws bytes.
#define ATTN_STEP(KC0, KC1, KC2, KC3, VC0, VC1, VC2, VC3,                       \
                  KN0, KN1, KN2, KN3, VN0, VN1, VN2, VN3, T)                    \
  {                                                                             \
    KN0 = *(const bf16x8*)(kp);                                                 \
    KN1 = *(const bf16x8*)(kp + 16);                                            \
    KN2 = *(const bf16x8*)(kp + 32);                                            \
    KN3 = *(const bf16x8*)(kp + 48);                                            \
    VN0 = *(const bf16x8*)(vp);                                                 \
    VN1 = *(const bf16x8*)(vp + 16);                                            \
    VN2 = *(const bf16x8*)(vp + 32 * 2048);                                     \
    VN3 = *(const bf16x8*)(vp + 32 * 2048 + 16);                                \
    kp += 4 * 32 * 64;                                                          \
    vp += 4 * 32;                                                               \
    __builtin_amdgcn_sched_barrier(0);                                          \
    __builtin_amdgcn_s_setprio(1);                                              \
    f32x16 st = {};                                                             \
    st = MFMA32(KC0, qB[0], st);                                                \
    st = MFMA32(KC1, qB[1], st);                                                \
    st = MFMA32(KC2, qB[2], st);                                                \
    st = MFMA32(KC3, qB[3], st);                                                \
    __builtin_amdgcn_s_setprio(0);                                              \
    float s[16];                                                                \
    _Pragma("unroll") for (int r = 0; r < 16; ++r) s[r] = st[r];                \
    if ((T) == nt - 1) {                                                        \
      _Pragma("unroll") for (int r = 0; r < 16; ++r) {                          \
        int key = (r & 3) + 8 * (r >> 2) + 4 * h;                               \
        if (key > l31) s[r] = -1e30f;                                           \
      }                                                                         \
    }                                                                           \
    float mx = s[0];                                                            \
    _Pragma("unroll") for (int r = 1; r < 16; ++r) mx = fmaxf(mx, s[r]);        \
    mx = fmaxf(mx, __shfl_xor(mx, 32));                                         \
    if (__any(mx > m_run + 8.f)) {                                              \
      float mnew = fmaxf(m_run, mx);                                            \
      float alpha = exp2f(m_run - mnew);                                        \
      _Pragma("unroll") for (int r = 0; r < 16; ++r) {                          \
        yacc0[r] *= alpha;                                                      \
        yacc1[r] *= alpha;                                                      \
      }                                                                         \
      l_run *= alpha;                                                           \
      m_run = mnew;                                                             \
    }                                                                           \
    float ls = 0.f;                                                             \
    _Pragma("unroll") for (int r = 0; r < 16; ++r) {                            \
      s[r] = exp2f(s[r] - m_run);                                               \
      ls += s[r];                                                               \
    }                                                                           \
    ls += __shfl_xor(ls, 32);                                                   \
    l_run += ls;                                                                \
    unsigned pk0 = cvtpk(s[0], s[1]), pk1 = cvtpk(s[2], s[3]);                  \
    unsigned pk2 = cvtpk(s[4], s[5]), pk3 = cvtpk(s[6], s[7]);                  \
    unsigned pk4 = cvtpk(s[8], s[9]), pk5 = cvtpk(s[10], s[11]);                \
    unsigned pk6 = cvtpk(s[12], s[13]), pk7 = cvtpk(s[14], s[15]);              \
    swap32(pk0, pk2);                                                           \
    swap32(pk1, pk3);                                                           \
    swap32(pk4, pk6);                                                           \
    swap32(pk5, pk7);                                                           \
    U8 u0, u1;                                                                  \
    u0.u[0] = pk0; u0.u[1] = pk1; u0.u[2] = pk2; u0.u[3] = pk3;                 \
    u1.u[0] = pk4; u1.u[1] = pk5; u1.u[2] = pk6; u1.u[3] = pk7;                 \
    __builtin_amdgcn_s_setprio(1);                                              \
    yacc0 = MFMA32(VC0, u0.v, yacc0);                                           \
    yacc0 = MFMA32(VC1, u1.v, yacc0);                                           \
    yacc1 = MFMA32(VC2, u0.v, yacc1);                                           \
    yacc1 = MFMA32(VC3, u1.v, yacc1);                                           \
    __builtin_amdgcn_s_setprio(0);                                              \
  }

__global__ __launch_bounds__(256, 3) void attn_kernel(
    const unsigned short* __restrict__ qb, const unsigned short* __restrict__ kb,
    const unsigned short* __restrict__ vtb, unsigned short* __restrict__ y_att) {
  __shared__ float ml_lds[3][2][32];
  __shared__ __align__(16) float y_lds[3][32][64];  // [wave-1][q][d] XOR-swizzled
  const int tid = threadIdx.x, lane = tid & 63, w = tid >> 6;
  const int u = (int)blockIdx.x;  // 0..2047
  // XCD-aware map: each XCD owns 4 heads -> K/V working set ~2MB fits its L2
  const int xcd = u & 7, sl = u >> 3;
  const int bh = (xcd << 2) | (sl & 3);
  const int qt = 63 - (sl >> 2);  // heaviest q-tiles first
  const int q0 = qt * 32;
  const int l31 = lane & 31, h = lane >> 5;
  const size_t base_off = (size_t)bh * (2048 * 64);
  const unsigned short* Q = qb + base_off;
  const unsigned short* Kp = kb + base_off;
  const unsigned short* Vt = vtb + base_off;  // [64][2048]
  const int nt = qt + 1;

  bf16x8 qB[4];
#pragma unroll
  for (int c = 0; c < 4; ++c)
    qB[c] = *(const bf16x8*)(Q + (size_t)(q0 + l31) * 64 + c * 16 + h * 8);

  f32x16 yacc0 = {}, yacc1 = {};
  float m_run = -1e30f, l_run = 0.f;

  int t = w;
  if (t < nt) {
    const unsigned short* kp = Kp + (size_t)(t * 32 + l31) * 64 + h * 8;
    const unsigned short* vp = Vt + (size_t)l31 * 2048 + t * 32 + h * 8;
    bf16x8 ka0 = *(const bf16x8*)(kp);
    bf16x8 ka1 = *(const bf16x8*)(kp + 16);
    bf16x8 ka2 = *(const bf16x8*)(kp + 32);
    bf16x8 ka3 = *(const bf16x8*)(kp + 48);
    bf16x8 va0 = *(const bf16x8*)(vp);
    bf16x8 va1 = *(const bf16x8*)(vp + 16);
    bf16x8 va2 = *(const bf16x8*)(vp + 32 * 2048);
    bf16x8 va3 = *(const bf16x8*)(vp + 32 * 2048 + 16);
    kp += 4 * 32 * 64;
    vp += 4 * 32;
    bf16x8 kb0, kb1, kb2, kb3, vb0, vb1, vb2, vb3;
    while (true) {
      ATTN_STEP(ka0, ka1, ka2, ka3, va0, va1, va2, va3,
                kb0, kb1, kb2, kb3, vb0, vb1, vb2, vb3, t);
      t += 4;
      if (t >= nt) break;
      ATTN_STEP(kb0, kb1, kb2, kb3, vb0, vb1, vb2, vb3,
                ka0, ka1, ka2, ka3, va0, va1, va2, va3, t);
      t += 4;
      if (t >= nt) break;
    }
  }

  // ---- cross-wave merge (flash-decoding combine) ----
  if (w > 0) {
    if (h == 0) {
      ml_lds[w - 1][0][l31] = m_run;
      ml_lds[w - 1][1][l31] = l_run;
    }
    float* row = &y_lds[w - 1][l31][0];
#pragma unroll
    for (int rg = 0; rg < 4; ++rg) {
      int d0 = 8 * rg + 4 * h;
      float4 a, b;
      a.x = yacc0[4 * rg + 0]; a.y = yacc0[4 * rg + 1];
      a.z = yacc0[4 * rg + 2]; a.w = yacc0[4 * rg + 3];
      b.x = yacc1[4 * rg + 0]; b.y = yacc1[4 * rg + 1];
      b.z = yacc1[4 * rg + 2]; b.w = yacc1[4 * rg + 3];
      *(float4*)(row + (d0 ^ ((l31 & 7) << 2))) = a;
      *(float4*)(row + ((d0 + 32) ^ ((l31 & 7) << 2))) = b;
    }
  }
  __syncthreads();
  if (w == 0) {
#pragma unroll
    for (int ww = 0; ww < 3; ++ww) {
      float m_w = ml_lds[ww][0][l31], l_w = ml_lds[ww][1][l31];
      float mnew = fmaxf(m_run, m_w);
      float a0 = exp2f(m_run - mnew), a1 = exp2f(m_w - mnew);
      m_run = mnew;
      l_run = l_run * a0 + l_w * a1;
      const float* row = &y_lds[ww][l31][0];
#pragma unroll
      for (int rg = 0; rg < 4; ++rg) {
        int d0 = 8 * rg + 4 * h;
        float4 a = *(const float4*)(row + (d0 ^ ((l31 & 7) << 2)));
        float4 b = *(const float4*)(row + ((d0 + 32) ^ ((l31 & 7) << 2)));
        yacc0[4 * rg + 0] = yacc0[4 * rg + 0] * a0 + a.x * a1;
        yacc0[4 * rg + 1] = yacc0[4 * rg + 1] * a0 + a.y * a1;
        yacc0[4 * rg + 2] = yacc0[4 * rg + 2] * a0 + a.z * a1;
        yacc0[4 * rg + 3] = yacc0[4 * rg + 3] * a0 + a.w * a1;
        yacc1[4 * rg + 0] = yacc1[4 * rg + 0] * a0 + b.x * a1;
        yacc1[4 * rg + 1] = yacc1[4 * rg + 1] * a0 + b.y * a1;
        yacc1[4 * rg + 2] = yacc1[4 * rg + 2] * a0 + b.z * a1;
        yacc1[4 * rg + 3] = yacc1[4 * rg + 3] * a0 + b.w * a1;
      }
    }

    float inv = 1.f / l_run;
    const int b = bh >> 4, head = bh & 15;
    size_t rowb = ((size_t)(b * 2048 + q0 + l31) * 16 + head) * 64;
#pragma unroll
    for (int rg = 0; rg < 4; ++rg) {
      int d0 = 8 * rg + 4 * h;
      ushort4 o0, o1;
      o0.x = f2b(yacc0[4 * rg + 0] * inv);
      o0.y = f2b(yacc0[4 * rg + 1] * inv);
      o0.z = f2b(yacc0[4 * rg + 2] * inv);
      o0.w = f2b(yacc0[4 * rg + 3] * inv);
      *(ushort4*)(y_att + rowb + d0) = o0;
      o1.x = f2b(yacc1[4 * rg + 0] * inv);
      o1.y = f2b(yacc1[4 * rg + 1] * inv);
      o1.z = f2b(yacc1[4 * rg + 2] * inv);
      o1.w = f2b(yacc1[4 * rg + 3] * inv);
      *(ushort4*)(y_att + rowb + 32 + d0) = o1;
    }
  }
}

// ---------- launcher ----------
extern "C" void kernel_launch(void* const* d_in, const int* in_sizes, int n_in,
                              void* d_out, int out_size, void* d_ws, size_t ws_size,
                              hipStream_t stream) {
  const float* x = (const float*)d_in[0];
  const float* W_qkv = (const float*)d_in[1];
  const float* b_qkv = (const float*)d_in[2];
  const float* W_out = (const float*)d_in[3];
  const float* b_out = (const float*)d_in[4];

  float* y_out = (float*)d_out;                 // [2,2048,1024]
  float* k_out = y_out + 4194304;               // [2,16,2048,64]
  float* v_out = y_out + 8388608;               // [2,16,2048,64]

  unsigned short* x_bf = (unsigned short*)d_ws;       // [4096,1024]
  unsigned short* wqkv_t = x_bf + 4194304;            // [3072,1024]
  unsigned short* wout_t = wqkv_t + 3145728;          // [1024,1024]
  unsigned short* q_bf = wout_t + 1048576;            // [B,H,T,Dh] (pre-scaled)
  unsigned short* k_bf = q_bf + 4194304;              // [B,H,T,Dh]
  unsigned short* vt_bf = k_bf + 4194304;             // [B,H,Dh,T]
  unsigned short* y_att = vt_bf + 4194304;            // [B,T,H*Dh]

  conv_bf16_kernel<<<4096, 256, 0, stream>>>(x, x_bf, 4194304);
  transpose_bf16_kernel<<<dim3(96, 32), dim3(32, 32), 0, stream>>>(W_qkv, wqkv_t, 1024, 3072);
  transpose_bf16_kernel<<<dim3(32, 32), dim3(32, 32), 0, stream>>>(W_out, wout_t, 1024, 1024);
  gemm_bf16_kernel<0><<<dim3(24, 32), 256, 0, stream>>>(
      x_bf, wqkv_t, b_qkv, 4096, 3072, 1024, q_bf, k_bf, vt_bf, k_out, v_out, nullptr);
  attn_kernel<<<2048, 256, 0, stream>>>(q_bf, k_bf, vt_bf, y_att);
  gemm_bf16_kernel<1><<<dim3(8, 32), 256, 0, stream>>>(
      y_att, wout_t, b_out, 4096, 1024, 1024, nullptr, nullptr, nullptr, nullptr, nullptr, y_out);
}

// Round 6
// 144.671 us; speedup vs baseline: 1.1094x; 1.1094x over previous
//
#include <hip/hip_runtime.h>

// ---------- types ----------
typedef __attribute__((ext_vector_type(8))) short bf16x8;   // 8 bf16 = 4 VGPR
typedef __attribute__((ext_vector_type(4))) float f32x4;
typedef __attribute__((ext_vector_type(16))) float f32x16;

#define MFMA16(A, B, C) __builtin_amdgcn_mfma_f32_16x16x32_bf16((A), (B), (C), 0, 0, 0)
#define MFMA32(A, B, C) __builtin_amdgcn_mfma_f32_32x32x16_bf16((A), (B), (C), 0, 0, 0)

union U8 { unsigned u[4]; bf16x8 v; };

// fp32 -> bf16 (round-to-nearest-even), header-independent
__device__ __forceinline__ unsigned short f2b(float f) {
  unsigned u = __builtin_bit_cast(unsigned, f);
  unsigned r = (u + 0x7fffu + ((u >> 16) & 1u)) >> 16;
  return (unsigned short)r;
}

// packed f32x2 -> bf16x2
__device__ __forceinline__ unsigned cvtpk(float lo, float hi) {
  unsigned r;
  asm("v_cvt_pk_bf16_f32 %0, %1, %2" : "=v"(r) : "v"(lo), "v"(hi));
  return r;
}
// exchange a.hi-half <-> b.lo-half across lane32 boundary
__device__ __forceinline__ void swap32(unsigned& a, unsigned& b) {
  asm("v_permlane32_swap_b32 %0, %1" : "+v"(a), "+v"(b));
}

// async global->LDS, 16B per lane. dest = wave-uniform base + lane*16
__device__ __forceinline__ void gload16(const void* g, void* l) {
  __builtin_amdgcn_global_load_lds(
      (const __attribute__((address_space(1))) void*)g,
      (__attribute__((address_space(3))) void*)l, 16, 0, 0);
}

// ---------- pre-pass: fp32 -> bf16 (vectorized) ----------
__global__ void conv_bf16_kernel(const float* __restrict__ src,
                                 unsigned short* __restrict__ dst, int n) {
  int i = (blockIdx.x * blockDim.x + threadIdx.x) * 4;
  if (i < n) {
    float4 v = *(const float4*)(src + i);
    ushort4 o;
    o.x = f2b(v.x); o.y = f2b(v.y); o.z = f2b(v.z); o.w = f2b(v.w);
    *(ushort4*)(dst + i) = o;
  }
}

// ---------- pre-pass: transpose fp32 [1024][C] -> bf16 [C][1024], both W ----
__global__ __launch_bounds__(1024) void transpose2_bf16_kernel(
    const float* __restrict__ s1, unsigned short* __restrict__ d1,
    const float* __restrict__ s2, unsigned short* __restrict__ d2) {
  __shared__ unsigned short t[32][33];
  int bx = (int)blockIdx.x;
  const float* src;
  unsigned short* dst;
  int C;
  if (bx < 96) { src = s1; dst = d1; C = 3072; }
  else         { src = s2; dst = d2; C = 1024; bx -= 96; }
  int x = threadIdx.x, y = threadIdx.y;
  int c0 = bx * 32, r0 = blockIdx.y * 32;
  t[y][x] = f2b(src[(size_t)(r0 + y) * C + c0 + x]);
  __syncthreads();
  dst[(size_t)(c0 + y) * 1024 + r0 + x] = t[x][y];
}

// ---------- GEMM: C[M,N] = A[M,K] * Bt[N,K]^T (+bias), bf16 MFMA ----------
template <int MODE>
__global__ __launch_bounds__(256, 2) void gemm_bf16_kernel(
    const unsigned short* __restrict__ A, const unsigned short* __restrict__ Bt,
    const float* __restrict__ bias, int M, int N, int K,
    unsigned short* __restrict__ q_bf, unsigned short* __restrict__ k_bf,
    unsigned short* __restrict__ vt_bf, float* __restrict__ k_out,
    float* __restrict__ v_out, float* __restrict__ y_out) {
  __shared__ __align__(16) unsigned short As[128 * 64];
  __shared__ __align__(16) unsigned short Bs[128 * 64];
  const int tid = threadIdx.x;
  const int lane = tid & 63, wid = tid >> 6;
  const int wr = wid >> 1, wc = wid & 1;
  const int l15 = lane & 15, lg = lane >> 4;
  const int m0 = blockIdx.y * 128, n0 = blockIdx.x * 128;

  f32x4 acc[4][4] = {};

  int rowS[4], colS[4];
#pragma unroll
  for (int j = 0; j < 4; ++j) {
    int L = j * 4096 + wid * 1024 + lane * 16;  // linear LDS byte
    int row = L >> 7;
    int c = (L & 127) ^ ((row & 7) << 4);
    rowS[j] = row;
    colS[j] = c >> 1;  // bf16 elements
  }

  for (int kt = 0; kt < K; kt += 64) {
    __syncthreads();
#pragma unroll
    for (int j = 0; j < 4; ++j) {
      gload16(A + (size_t)(m0 + rowS[j]) * K + kt + colS[j],
              (char*)As + j * 4096 + wid * 1024);
      gload16(Bt + (size_t)(n0 + rowS[j]) * K + kt + colS[j],
              (char*)Bs + j * 4096 + wid * 1024);
    }
    __syncthreads();

    bf16x8 af[4][2], bfr[4][2];
#pragma unroll
    for (int i = 0; i < 4; ++i)
#pragma unroll
      for (int kk = 0; kk < 2; ++kk) {
        int ra = wr * 64 + i * 16 + l15;
        int cb = kk * 64 + lg * 16;
        af[i][kk] = *(const bf16x8*)((const char*)As + ra * 128 + (cb ^ ((ra & 7) << 4)));
        int rb = wc * 64 + i * 16 + l15;
        bfr[i][kk] = *(const bf16x8*)((const char*)Bs + rb * 128 + (cb ^ ((rb & 7) << 4)));
      }
#pragma unroll
    for (int mi = 0; mi < 4; ++mi)
#pragma unroll
      for (int ni = 0; ni < 4; ++ni)
#pragma unroll
        for (int kk = 0; kk < 2; ++kk)
          acc[mi][ni] = MFMA16(af[mi][kk], bfr[ni][kk], acc[mi][ni]);
  }

#pragma unroll
  for (int ni = 0; ni < 4; ++ni) {
    int gn = n0 + wc * 64 + ni * 16 + l15;
    float bv = bias[gn];
    if (MODE == 0) {
      int which = gn >> 10, rem = gn & 1023;
      int h = rem >> 6, dh = rem & 63;
#pragma unroll
      for (int mi = 0; mi < 4; ++mi) {
        int gmb = m0 + wr * 64 + mi * 16 + lg * 4;
#pragma unroll
        for (int r = 0; r < 4; ++r) {
          int gm = gmb + r;
          int b = gm >> 11, t = gm & 2047;
          float val = acc[mi][ni][r] + bv;
          size_t idx = ((size_t)((b * 16 + h) * 2048 + t)) * 64 + dh;
          if (which == 0) {
            q_bf[idx] = f2b(val * 0.18033688f);  // pre-scale by 1/sqrt(64)*log2(e)
          } else if (which == 1) {
            k_out[idx] = val;
            k_bf[idx] = f2b(val);
          } else {
            v_out[idx] = val;
            vt_bf[((size_t)(b * 16 + h) * 64 + dh) * 2048 + t] = f2b(val);
          }
        }
      }
    } else {
#pragma unroll
      for (int mi = 0; mi < 4; ++mi) {
        int gmb = m0 + wr * 64 + mi * 16 + lg * 4;
#pragma unroll
        for (int r = 0; r < 4; ++r)
          y_out[(size_t)(gmb + r) * N + gn] = acc[mi][ni][r] + bv;
      }
    }
  }
}

// ---------- causal flash attention: split-K across the 4 waves ----------
// Block = (q-tile of 32 rows, head). Wave w handles KV tiles t = w, w+4, ...
// XCD-aware map: each XCD owns 4 heads -> K/V working set ~2MB fits its L2.
// Per tile: S^T = K*Q^T (two independent 2-MFMA chains), register-only
// softmax (cvt_pk + permlane32_swap), PV via 32x32x16; setprio around MFMAs.
// Partial (m, l, O) merged across waves through swizzled LDS by wave 0.
__global__ __launch_bounds__(256, 4) void attn_kernel(
    const unsigned short* __restrict__ qb, const unsigned short* __restrict__ kb,
    const unsigned short* __restrict__ vtb, unsigned short* __restrict__ y_att) {
  __shared__ float ml_lds[3][2][32];
  __shared__ __align__(16) float y_lds[3][32][64];  // [wave-1][q][d] XOR-swizzled
  const int tid = threadIdx.x, lane = tid & 63, w = tid >> 6;
  const int u = (int)blockIdx.x;  // 0..2047
  const int xcd = u & 7, sl = u >> 3;
  const int bh = (xcd << 2) | (sl & 3);
  const int qt = 63 - (sl >> 2);  // heaviest q-tiles first
  const int q0 = qt * 32;
  const int l31 = lane & 31, h = lane >> 5;
  const size_t base_off = (size_t)bh * (2048 * 64);
  const unsigned short* Q = qb + base_off;
  const unsigned short* Kp = kb + base_off;
  const unsigned short* Vt = vtb + base_off;  // [64][2048]
  const int nt = qt + 1;

  bf16x8 qB[4];
#pragma unroll
  for (int c = 0; c < 4; ++c)
    qB[c] = *(const bf16x8*)(Q + (size_t)(q0 + l31) * 64 + c * 16 + h * 8);

  f32x16 yacc0 = {}, yacc1 = {};
  float m_run = -1e30f, l_run = 0.f;

  int t = w;
  const unsigned short* kp = Kp + (size_t)(t * 32 + l31) * 64 + h * 8;
  const unsigned short* vp = Vt + (size_t)l31 * 2048 + t * 32 + h * 8;

  for (; t < nt; t += 4) {
    bf16x8 kc0 = *(const bf16x8*)(kp);
    bf16x8 kc1 = *(const bf16x8*)(kp + 16);
    bf16x8 kc2 = *(const bf16x8*)(kp + 32);
    bf16x8 kc3 = *(const bf16x8*)(kp + 48);
    bf16x8 vf00 = *(const bf16x8*)(vp);
    bf16x8 vf01 = *(const bf16x8*)(vp + 16);
    bf16x8 vf10 = *(const bf16x8*)(vp + 32 * 2048);
    bf16x8 vf11 = *(const bf16x8*)(vp + 32 * 2048 + 16);
    kp += 4 * 32 * 64;  // +4 tiles of K rows
    vp += 4 * 32;       // +4 tiles of keys

    // QK^T: two independent chains, summed
    __builtin_amdgcn_s_setprio(1);
    f32x16 sa = {}, sb = {};
    sa = MFMA32(kc0, qB[0], sa);
    sb = MFMA32(kc2, qB[2], sb);
    sa = MFMA32(kc1, qB[1], sa);
    sb = MFMA32(kc3, qB[3], sb);
    __builtin_amdgcn_s_setprio(0);
    float s[16];
#pragma unroll
    for (int r = 0; r < 16; ++r) s[r] = sa[r] + sb[r];

    if (t == nt - 1) {  // diagonal tile: causal mask
#pragma unroll
      for (int r = 0; r < 16; ++r) {
        int key = (r & 3) + 8 * (r >> 2) + 4 * h;
        if (key > l31) s[r] = -1e30f;
      }
    }
    float mx = s[0];
#pragma unroll
    for (int r = 1; r < 16; ++r) mx = fmaxf(mx, s[r]);
    mx = fmaxf(mx, __shfl_xor(mx, 32));
    if (__any(mx > m_run + 8.f)) {  // defer-max
      float mnew = fmaxf(m_run, mx);
      float alpha = exp2f(m_run - mnew);
#pragma unroll
      for (int r = 0; r < 16; ++r) {
        yacc0[r] *= alpha;
        yacc1[r] *= alpha;
      }
      l_run *= alpha;
      m_run = mnew;
    }
    float ls = 0.f;
#pragma unroll
    for (int r = 0; r < 16; ++r) {
      s[r] = exp2f(s[r] - m_run);
      ls += s[r];
    }
    ls += __shfl_xor(ls, 32);
    l_run += ls;

    unsigned pk0 = cvtpk(s[0], s[1]), pk1 = cvtpk(s[2], s[3]);
    unsigned pk2 = cvtpk(s[4], s[5]), pk3 = cvtpk(s[6], s[7]);
    unsigned pk4 = cvtpk(s[8], s[9]), pk5 = cvtpk(s[10], s[11]);
    unsigned pk6 = cvtpk(s[12], s[13]), pk7 = cvtpk(s[14], s[15]);
    swap32(pk0, pk2);
    swap32(pk1, pk3);
    swap32(pk4, pk6);
    swap32(pk5, pk7);
    U8 u0, u1;
    u0.u[0] = pk0; u0.u[1] = pk1; u0.u[2] = pk2; u0.u[3] = pk3;
    u1.u[0] = pk4; u1.u[1] = pk5; u1.u[2] = pk6; u1.u[3] = pk7;
    __builtin_amdgcn_s_setprio(1);
    yacc0 = MFMA32(vf00, u0.v, yacc0);
    yacc0 = MFMA32(vf01, u1.v, yacc0);
    yacc1 = MFMA32(vf10, u0.v, yacc1);
    yacc1 = MFMA32(vf11, u1.v, yacc1);
    __builtin_amdgcn_s_setprio(0);
  }

  // ---- cross-wave merge (flash-decoding combine) ----
  if (w > 0) {
    if (h == 0) {
      ml_lds[w - 1][0][l31] = m_run;
      ml_lds[w - 1][1][l31] = l_run;
    }
    float* row = &y_lds[w - 1][l31][0];
#pragma unroll
    for (int rg = 0; rg < 4; ++rg) {
      int d0 = 8 * rg + 4 * h;
      float4 a, b;
      a.x = yacc0[4 * rg + 0]; a.y = yacc0[4 * rg + 1];
      a.z = yacc0[4 * rg + 2]; a.w = yacc0[4 * rg + 3];
      b.x = yacc1[4 * rg + 0]; b.y = yacc1[4 * rg + 1];
      b.z = yacc1[4 * rg + 2]; b.w = yacc1[4 * rg + 3];
      *(float4*)(row + (d0 ^ ((l31 & 7) << 2))) = a;
      *(float4*)(row + ((d0 + 32) ^ ((l31 & 7) << 2))) = b;
    }
  }
  __syncthreads();
  if (w == 0) {
#pragma unroll
    for (int ww = 0; ww < 3; ++ww) {
      float m_w = ml_lds[ww][0][l31], l_w = ml_lds[ww][1][l31];
      float mnew = fmaxf(m_run, m_w);
      float a0 = exp2f(m_run - mnew), a1 = exp2f(m_w - mnew);
      m_run = mnew;
      l_run = l_run * a0 + l_w * a1;
      const float* row = &y_lds[ww][l31][0];
#pragma unroll
      for (int rg = 0; rg < 4; ++rg) {
        int d0 = 8 * rg + 4 * h;
        float4 a = *(const float4*)(row + (d0 ^ ((l31 & 7) << 2)));
        float4 b = *(const float4*)(row + ((d0 + 32) ^ ((l31 & 7) << 2)));
        yacc0[4 * rg + 0] = yacc0[4 * rg + 0] * a0 + a.x * a1;
        yacc0[4 * rg + 1] = yacc0[4 * rg + 1] * a0 + a.y * a1;
        yacc0[4 * rg + 2] = yacc0[4 * rg + 2] * a0 + a.z * a1;
        yacc0[4 * rg + 3] = yacc0[4 * rg + 3] * a0 + a.w * a1;
        yacc1[4 * rg + 0] = yacc1[4 * rg + 0] * a0 + b.x * a1;
        yacc1[4 * rg + 1] = yacc1[4 * rg + 1] * a0 + b.y * a1;
        yacc1[4 * rg + 2] = yacc1[4 * rg + 2] * a0 + b.z * a1;
        yacc1[4 * rg + 3] = yacc1[4 * rg + 3] * a0 + b.w * a1;
      }
    }

    float inv = 1.f / l_run;
    const int b = bh >> 4, head = bh & 15;
    size_t rowb = ((size_t)(b * 2048 + q0 + l31) * 16 + head) * 64;
#pragma unroll
    for (int rg = 0; rg < 4; ++rg) {
      int d0 = 8 * rg + 4 * h;
      ushort4 o0, o1;
      o0.x = f2b(yacc0[4 * rg + 0] * inv);
      o0.y = f2b(yacc0[4 * rg + 1] * inv);
      o0.z = f2b(yacc0[4 * rg + 2] * inv);
      o0.w = f2b(yacc0[4 * rg + 3] * inv);
      *(ushort4*)(y_att + rowb + d0) = o0;
      o1.x = f2b(yacc1[4 * rg + 0] * inv);
      o1.y = f2b(yacc1[4 * rg + 1] * inv);
      o1.z = f2b(yacc1[4 * rg + 2] * inv);
      o1.w = f2b(yacc1[4 * rg + 3] * inv);
      *(ushort4*)(y_att + rowb + 32 + d0) = o1;
    }
  }
}

// ---------- launcher ----------
extern "C" void kernel_launch(void* const* d_in, const int* in_sizes, int n_in,
                              void* d_out, int out_size, void* d_ws, size_t ws_size,
                              hipStream_t stream) {
  const float* x = (const float*)d_in[0];
  const float* W_qkv = (const float*)d_in[1];
  const float* b_qkv = (const float*)d_in[2];
  const float* W_out = (const float*)d_in[3];
  const float* b_out = (const float*)d_in[4];

  float* y_out = (float*)d_out;                 // [2,2048,1024]
  float* k_out = y_out + 4194304;               // [2,16,2048,64]
  float* v_out = y_out + 8388608;               // [2,16,2048,64]

  unsigned short* x_bf = (unsigned short*)d_ws;       // [4096,1024]
  unsigned short* wqkv_t = x_bf + 4194304;            // [3072,1024]
  unsigned short* wout_t = wqkv_t + 3145728;          // [1024,1024]
  unsigned short* q_bf = wout_t + 1048576;            // [B,H,T,Dh] (pre-scaled)
  unsigned short* k_bf = q_bf + 4194304;              // [B,H,T,Dh]
  unsigned short* vt_bf = k_bf + 4194304;             // [B,H,Dh,T]
  unsigned short* y_att = vt_bf + 4194304;            // [B,T,H*Dh]

  conv_bf16_kernel<<<4096, 256, 0, stream>>>(x, x_bf, 4194304);
  transpose2_bf16_kernel<<<dim3(128, 32), dim3(32, 32), 0, stream>>>(
      W_qkv, wqkv_t, W_out, wout_t);
  gemm_bf16_kernel<0><<<dim3(24, 32), 256, 0, stream>>>(
      x_bf, wqkv_t, b_qkv, 4096, 3072, 1024, q_bf, k_bf, vt_bf, k_out, v_out, nullptr);
  attn_kernel<<<2048, 256, 0, stream>>>(q_bf, k_bf, vt_bf, y_att);
  gemm_bf16_kernel<1><<<dim3(8, 32), 256, 0, stream>>>(
      y_att, wout_t, b_out, 4096, 1024, 1024, nullptr, nullptr, nullptr, nullptr, nullptr, y_out);
}

// Round 7
// 134.285 us; speedup vs baseline: 1.1952x; 1.0773x over previous
//
#include <hip/hip_runtime.h>

// ---------- types ----------
typedef __attribute__((ext_vector_type(8))) short bf16x8;   // 8 bf16 = 4 VGPR
typedef __attribute__((ext_vector_type(4))) float f32x4;
typedef __attribute__((ext_vector_type(16))) float f32x16;

#define MFMA16(A, B, C) __builtin_amdgcn_mfma_f32_16x16x32_bf16((A), (B), (C), 0, 0, 0)
#define MFMA32(A, B, C) __builtin_amdgcn_mfma_f32_32x32x16_bf16((A), (B), (C), 0, 0, 0)

union U8 { unsigned u[4]; bf16x8 v; };

// fp32 -> bf16 (round-to-nearest-even), header-independent
__device__ __forceinline__ unsigned short f2b(float f) {
  unsigned u = __builtin_bit_cast(unsigned, f);
  unsigned r = (u + 0x7fffu + ((u >> 16) & 1u)) >> 16;
  return (unsigned short)r;
}

// packed f32x2 -> bf16x2
__device__ __forceinline__ unsigned cvtpk(float lo, float hi) {
  unsigned r;
  asm("v_cvt_pk_bf16_f32 %0, %1, %2" : "=v"(r) : "v"(lo), "v"(hi));
  return r;
}
// exchange a.hi-half <-> b.lo-half across lane32 boundary
__device__ __forceinline__ void swap32(unsigned& a, unsigned& b) {
  asm("v_permlane32_swap_b32 %0, %1" : "+v"(a), "+v"(b));
}

// async global->LDS, 16B per lane. dest = wave-uniform base + lane*16
__device__ __forceinline__ void gload16(const void* g, void* l) {
  __builtin_amdgcn_global_load_lds(
      (const __attribute__((address_space(1))) void*)g,
      (__attribute__((address_space(3))) void*)l, 16, 0, 0);
}

// ---------- pre-pass: fp32 -> bf16 (vectorized) ----------
__global__ void conv_bf16_kernel(const float* __restrict__ src,
                                 unsigned short* __restrict__ dst, int n) {
  int i = (blockIdx.x * blockDim.x + threadIdx.x) * 4;
  if (i < n) {
    float4 v = *(const float4*)(src + i);
    ushort4 o;
    o.x = f2b(v.x); o.y = f2b(v.y); o.z = f2b(v.z); o.w = f2b(v.w);
    *(ushort4*)(dst + i) = o;
  }
}

// ---------- pre-pass: transpose fp32 [1024][C] -> bf16 [C][1024], both W ----
__global__ __launch_bounds__(1024) void transpose2_bf16_kernel(
    const float* __restrict__ s1, unsigned short* __restrict__ d1,
    const float* __restrict__ s2, unsigned short* __restrict__ d2) {
  __shared__ unsigned short t[32][33];
  int bx = (int)blockIdx.x;
  const float* src;
  unsigned short* dst;
  int C;
  if (bx < 96) { src = s1; dst = d1; C = 3072; }
  else         { src = s2; dst = d2; C = 1024; bx -= 96; }
  int x = threadIdx.x, y = threadIdx.y;
  int c0 = bx * 32, r0 = blockIdx.y * 32;
  t[y][x] = f2b(src[(size_t)(r0 + y) * C + c0 + x]);
  __syncthreads();
  dst[(size_t)(c0 + y) * 1024 + r0 + x] = t[x][y];
}

// ---------- GEMM: C[M,N] = A[M,K] * Bt[N,K]^T (+bias), bf16 MFMA ----------
template <int MODE>
__global__ __launch_bounds__(256, 2) void gemm_bf16_kernel(
    const unsigned short* __restrict__ A, const unsigned short* __restrict__ Bt,
    const float* __restrict__ bias, int M, int N, int K,
    unsigned short* __restrict__ q_bf, unsigned short* __restrict__ k_bf,
    unsigned short* __restrict__ vt_bf, float* __restrict__ k_out,
    float* __restrict__ v_out, float* __restrict__ y_out) {
  __shared__ __align__(16) unsigned short As[128 * 64];
  __shared__ __align__(16) unsigned short Bs[128 * 64];
  const int tid = threadIdx.x;
  const int lane = tid & 63, wid = tid >> 6;
  const int wr = wid >> 1, wc = wid & 1;
  const int l15 = lane & 15, lg = lane >> 4;
  const int m0 = blockIdx.y * 128, n0 = blockIdx.x * 128;

  f32x4 acc[4][4] = {};

  int rowS[4], colS[4];
#pragma unroll
  for (int j = 0; j < 4; ++j) {
    int L = j * 4096 + wid * 1024 + lane * 16;  // linear LDS byte
    int row = L >> 7;
    int c = (L & 127) ^ ((row & 7) << 4);
    rowS[j] = row;
    colS[j] = c >> 1;  // bf16 elements
  }

  for (int kt = 0; kt < K; kt += 64) {
    __syncthreads();
#pragma unroll
    for (int j = 0; j < 4; ++j) {
      gload16(A + (size_t)(m0 + rowS[j]) * K + kt + colS[j],
              (char*)As + j * 4096 + wid * 1024);
      gload16(Bt + (size_t)(n0 + rowS[j]) * K + kt + colS[j],
              (char*)Bs + j * 4096 + wid * 1024);
    }
    __syncthreads();

    bf16x8 af[4][2], bfr[4][2];
#pragma unroll
    for (int i = 0; i < 4; ++i)
#pragma unroll
      for (int kk = 0; kk < 2; ++kk) {
        int ra = wr * 64 + i * 16 + l15;
        int cb = kk * 64 + lg * 16;
        af[i][kk] = *(const bf16x8*)((const char*)As + ra * 128 + (cb ^ ((ra & 7) << 4)));
        int rb = wc * 64 + i * 16 + l15;
        bfr[i][kk] = *(const bf16x8*)((const char*)Bs + rb * 128 + (cb ^ ((rb & 7) << 4)));
      }
#pragma unroll
    for (int mi = 0; mi < 4; ++mi)
#pragma unroll
      for (int ni = 0; ni < 4; ++ni)
#pragma unroll
        for (int kk = 0; kk < 2; ++kk)
          acc[mi][ni] = MFMA16(af[mi][kk], bfr[ni][kk], acc[mi][ni]);
  }

#pragma unroll
  for (int ni = 0; ni < 4; ++ni) {
    int gn = n0 + wc * 64 + ni * 16 + l15;
    float bv = bias[gn];
    if (MODE == 0) {
      int which = gn >> 10, rem = gn & 1023;
      int h = rem >> 6, dh = rem & 63;
#pragma unroll
      for (int mi = 0; mi < 4; ++mi) {
        int gmb = m0 + wr * 64 + mi * 16 + lg * 4;
#pragma unroll
        for (int r = 0; r < 4; ++r) {
          int gm = gmb + r;
          int b = gm >> 11, t = gm & 2047;
          float val = acc[mi][ni][r] + bv;
          size_t idx = ((size_t)((b * 16 + h) * 2048 + t)) * 64 + dh;
          if (which == 0) {
            q_bf[idx] = f2b(val * 0.18033688f);  // pre-scale by 1/sqrt(64)*log2(e)
          } else if (which == 1) {
            k_out[idx] = val;
            k_bf[idx] = f2b(val);
          } else {
            v_out[idx] = val;
            vt_bf[((size_t)(b * 16 + h) * 64 + dh) * 2048 + t] = f2b(val);
          }
        }
      }
    } else {
#pragma unroll
      for (int mi = 0; mi < 4; ++mi) {
        int gmb = m0 + wr * 64 + mi * 16 + lg * 4;
#pragma unroll
        for (int r = 0; r < 4; ++r)
          y_out[(size_t)(gmb + r) * N + gn] = acc[mi][ni][r] + bv;
      }
    }
  }
}

// ---------- causal flash attention: LDS-staged, double-buffered ----------
// Block = (128 q-rows, head); 4 waves x 32 q-rows each, no split-K.
// KVBLK=64. K tile [64][128B] and V^T tile [64 d][128B] staged to LDS via
// async global_load_lds with XOR-swizzle (inverse-swizzled source, rule #21).
// Loop: stage(t+1) -> compute(t) -> barrier; stage latency hides under compute.
// Softmax fully in-register (cvt_pk + permlane32_swap, defer-max THR=8).
__global__ __launch_bounds__(256, 2) void attn_kernel(
    const unsigned short* __restrict__ qbuf, const unsigned short* __restrict__ kb,
    const unsigned short* __restrict__ vtb, unsigned short* __restrict__ y_att) {
  __shared__ __align__(16) char lds_k[2][8192];
  __shared__ __align__(16) char lds_v[2][8192];
  const int tid = threadIdx.x, lane = tid & 63, w = tid >> 6;
  const int u = (int)blockIdx.x;  // 0..511
  const int bh = ((u & 7) << 2) | ((u >> 3) & 3);  // XCD-grouped heads
  const int qb = 15 - (u >> 5);                    // heaviest q-blocks first
  const int l31 = lane & 31, h = lane >> 5;
  const int qw0 = qb * 128 + w * 32;               // this wave's first q row
  const size_t base_off = (size_t)bh * (2048 * 64);
  const unsigned short* Q = qbuf + base_off;
  const char* Kb = (const char*)(kb + base_off);   // [2048][128B]
  const char* Vb = (const char*)(vtb + base_off);  // [64][4096B]
  const int nt = 2 * qb + 2;
  const int my_last = (qw0 + 31) >> 6;  // last tile this wave computes

  // staging coords: LDS linear byte L holds global (row=L>>7, col=(L&127)^sw)
  int rowS[2], gcS[2];
#pragma unroll
  for (int j = 0; j < 2; ++j) {
    int L = tid * 16 + j * 4096;
    int row = L >> 7;
    rowS[j] = row;
    gcS[j] = (L & 127) ^ ((row & 7) << 4);
  }

#define STAGE(T, BUF)                                                           \
  {                                                                             \
    const int kv0_ = (T) * 64;                                                  \
    _Pragma("unroll") for (int j = 0; j < 2; ++j) {                             \
      gload16(Kb + (size_t)(kv0_ + rowS[j]) * 128 + gcS[j],                     \
              &lds_k[BUF][j * 4096 + tid * 16]);                                \
      gload16(Vb + (size_t)rowS[j] * 4096 + kv0_ * 2 + gcS[j],                  \
              &lds_v[BUF][j * 4096 + tid * 16]);                                \
    }                                                                           \
  }

  bf16x8 qB[4];
#pragma unroll
  for (int c = 0; c < 4; ++c)
    qB[c] = *(const bf16x8*)(Q + (size_t)(qw0 + l31) * 64 + c * 16 + h * 8);

  f32x16 yacc0 = {}, yacc1 = {};
  float m_run = -1e30f, l_run = 0.f;
  const int swz = (l31 & 7) << 4;

  STAGE(0, 0);
  __syncthreads();

  for (int t = 0; t < nt; ++t) {
    if (t + 1 < nt) STAGE(t + 1, (t + 1) & 1);
    if (t <= my_last) {
      const char* Kl = lds_k[t & 1];
      const char* Vl = lds_v[t & 1];
      // QK^T for both key-halves
      __builtin_amdgcn_s_setprio(1);
      f32x16 st0 = {}, st1 = {};
#pragma unroll
      for (int c = 0; c < 4; ++c) {
        bf16x8 k0 = *(const bf16x8*)(Kl + (size_t)l31 * 128 + ((c * 32 + h * 16) ^ swz));
        st0 = MFMA32(k0, qB[c], st0);
      }
#pragma unroll
      for (int c = 0; c < 4; ++c) {
        bf16x8 k1 = *(const bf16x8*)(Kl + (size_t)(32 + l31) * 128 + ((c * 32 + h * 16) ^ swz));
        st1 = MFMA32(k1, qB[c], st1);
      }
      __builtin_amdgcn_s_setprio(0);

      float s[32];
#pragma unroll
      for (int r = 0; r < 16; ++r) { s[r] = st0[r]; s[16 + r] = st1[r]; }
      if (t == my_last) {  // diagonal tile: causal mask
#pragma unroll
        for (int r = 0; r < 32; ++r) {
          int key = t * 64 + (r >> 4) * 32 + (r & 3) + 8 * ((r >> 2) & 3) + 4 * h;
          if (key > qw0 + l31) s[r] = -1e30f;
        }
      }
      float mx = s[0];
#pragma unroll
      for (int r = 1; r < 32; ++r) mx = fmaxf(mx, s[r]);
      mx = fmaxf(mx, __shfl_xor(mx, 32));
      if (__any(mx > m_run + 8.f)) {  // defer-max
        float mnew = fmaxf(m_run, mx);
        float alpha = exp2f(m_run - mnew);
#pragma unroll
        for (int r = 0; r < 16; ++r) { yacc0[r] *= alpha; yacc1[r] *= alpha; }
        l_run *= alpha;
        m_run = mnew;
      }
      float ls = 0.f;
#pragma unroll
      for (int r = 0; r < 32; ++r) {
        s[r] = exp2f(s[r] - m_run);
        ls += s[r];
      }
      ls += __shfl_xor(ls, 32);
      l_run += ls;

      // P -> bf16 fragments (keys chunked 16): half0 -> u00,u01; half1 -> u10,u11
      U8 pf[4];
      {
        unsigned pk0 = cvtpk(s[0], s[1]), pk1 = cvtpk(s[2], s[3]);
        unsigned pk2 = cvtpk(s[4], s[5]), pk3 = cvtpk(s[6], s[7]);
        unsigned pk4 = cvtpk(s[8], s[9]), pk5 = cvtpk(s[10], s[11]);
        unsigned pk6 = cvtpk(s[12], s[13]), pk7 = cvtpk(s[14], s[15]);
        swap32(pk0, pk2); swap32(pk1, pk3); swap32(pk4, pk6); swap32(pk5, pk7);
        pf[0].u[0] = pk0; pf[0].u[1] = pk1; pf[0].u[2] = pk2; pf[0].u[3] = pk3;
        pf[1].u[0] = pk4; pf[1].u[1] = pk5; pf[1].u[2] = pk6; pf[1].u[3] = pk7;
        unsigned qk0 = cvtpk(s[16], s[17]), qk1 = cvtpk(s[18], s[19]);
        unsigned qk2 = cvtpk(s[20], s[21]), qk3 = cvtpk(s[22], s[23]);
        unsigned qk4 = cvtpk(s[24], s[25]), qk5 = cvtpk(s[26], s[27]);
        unsigned qk6 = cvtpk(s[28], s[29]), qk7 = cvtpk(s[30], s[31]);
        swap32(qk0, qk2); swap32(qk1, qk3); swap32(qk4, qk6); swap32(qk5, qk7);
        pf[2].u[0] = qk0; pf[2].u[1] = qk1; pf[2].u[2] = qk2; pf[2].u[3] = qk3;
        pf[3].u[0] = qk4; pf[3].u[1] = qk5; pf[3].u[2] = qk6; pf[3].u[3] = qk7;
      }

      // PV: Y^T += V^T * P^T
      __builtin_amdgcn_s_setprio(1);
#pragma unroll
      for (int c = 0; c < 4; ++c) {
        bf16x8 v0 = *(const bf16x8*)(Vl + (size_t)l31 * 128 + ((c * 32 + h * 16) ^ swz));
        yacc0 = MFMA32(v0, pf[c].v, yacc0);
      }
#pragma unroll
      for (int c = 0; c < 4; ++c) {
        bf16x8 v1 = *(const bf16x8*)(Vl + (size_t)(32 + l31) * 128 + ((c * 32 + h * 16) ^ swz));
        yacc1 = MFMA32(v1, pf[c].v, yacc1);
      }
      __builtin_amdgcn_s_setprio(0);
    }
    __syncthreads();
  }
#undef STAGE

  float inv = 1.f / l_run;
  const int b = bh >> 4, head = bh & 15;
  size_t rowb = ((size_t)(b * 2048 + qw0 + l31) * 16 + head) * 64;
#pragma unroll
  for (int rg = 0; rg < 4; ++rg) {
    int d0 = 8 * rg + 4 * h;
    ushort4 o0, o1;
    o0.x = f2b(yacc0[4 * rg + 0] * inv);
    o0.y = f2b(yacc0[4 * rg + 1] * inv);
    o0.z = f2b(yacc0[4 * rg + 2] * inv);
    o0.w = f2b(yacc0[4 * rg + 3] * inv);
    *(ushort4*)(y_att + rowb + d0) = o0;
    o1.x = f2b(yacc1[4 * rg + 0] * inv);
    o1.y = f2b(yacc1[4 * rg + 1] * inv);
    o1.z = f2b(yacc1[4 * rg + 2] * inv);
    o1.w = f2b(yacc1[4 * rg + 3] * inv);
    *(ushort4*)(y_att + rowb + 32 + d0) = o1;
  }
}

// ---------- launcher ----------
extern "C" void kernel_launch(void* const* d_in, const int* in_sizes, int n_in,
                              void* d_out, int out_size, void* d_ws, size_t ws_size,
                              hipStream_t stream) {
  const float* x = (const float*)d_in[0];
  const float* W_qkv = (const float*)d_in[1];
  const float* b_qkv = (const float*)d_in[2];
  const float* W_out = (const float*)d_in[3];
  const float* b_out = (const float*)d_in[4];

  float* y_out = (float*)d_out;                 // [2,2048,1024]
  float* k_out = y_out + 4194304;               // [2,16,2048,64]
  float* v_out = y_out + 8388608;               // [2,16,2048,64]

  unsigned short* x_bf = (unsigned short*)d_ws;       // [4096,1024]
  unsigned short* wqkv_t = x_bf + 4194304;            // [3072,1024]
  unsigned short* wout_t = wqkv_t + 3145728;          // [1024,1024]
  unsigned short* q_bf = wout_t + 1048576;            // [B,H,T,Dh] (pre-scaled)
  unsigned short* k_bf = q_bf + 4194304;              // [B,H,T,Dh]
  unsigned short* vt_bf = k_bf + 4194304;             // [B,H,Dh,T]
  unsigned short* y_att = vt_bf + 4194304;            // [B,T,H*Dh]

  conv_bf16_kernel<<<4096, 256, 0, stream>>>(x, x_bf, 4194304);
  transpose2_bf16_kernel<<<dim3(128, 32), dim3(32, 32), 0, stream>>>(
      W_qkv, wqkv_t, W_out, wout_t);
  gemm_bf16_kernel<0><<<dim3(24, 32), 256, 0, stream>>>(
      x_bf, wqkv_t, b_qkv, 4096, 3072, 1024, q_bf, k_bf, vt_bf, k_out, v_out, nullptr);
  attn_kernel<<<512, 256, 0, stream>>>(q_bf, k_bf, vt_bf, y_att);
  gemm_bf16_kernel<1><<<dim3(8, 32), 256, 0, stream>>>(
      y_att, wout_t, b_out, 4096, 1024, 1024, nullptr, nullptr, nullptr, nullptr, nullptr, y_out);
}